// Round 1
// baseline (634.496 us; speedup 1.0000x reference)
//
#include <hip/hip_runtime.h>
#include <math.h>

// ---------------- problem constants ----------------
#define BATCH   256
#define SIGLEN  2048
#define L1OUT   1022   // conv1(2046) -> pool k3 s2
#define L2OUT   339    // conv2(1018) -> pool k3 s3
#define L3OUT   168    // conv3(337)  -> pool k3 s2
#define FCIN    10752  // 64*168

// conv12 tiling
#define TP2     32             // pooled conv2 outputs per block
#define NP2     (3*TP2)        // conv2 positions per block = 96
#define P1      (NP2+4)        // h1 positions needed = 100
#define XT      (2*P1+3)       // x positions needed  = 203

// ---------------- prep: weight transpose + BN fold ----------------
__launch_bounds__(256)
__global__ void prep_kernel(
    const float* __restrict__ conv1_b,
    const float* __restrict__ g1, const float* __restrict__ b1,
    const float* __restrict__ m1, const float* __restrict__ v1,
    const float* __restrict__ conv2_w, const float* __restrict__ conv2_b,
    const float* __restrict__ g2, const float* __restrict__ b2,
    const float* __restrict__ m2, const float* __restrict__ v2,
    const float* __restrict__ conv3_w, const float* __restrict__ conv3_b,
    const float* __restrict__ g3, const float* __restrict__ b3,
    const float* __restrict__ m3, const float* __restrict__ v3,
    float* __restrict__ w2t, float* __restrict__ w3t,
    float* __restrict__ so1, float* __restrict__ so2, float* __restrict__ so3)
{
    int tid = blockIdx.x * 256 + threadIdx.x;
    int stride = gridDim.x * 256;
    // w2t[ci*320 + k*64 + co] = conv2_w[co][ci][k]
    for (int i = tid; i < 64*128*5; i += stride) {
        int co = i / 640; int r = i - co*640; int ci = r / 5; int k = r - ci*5;
        w2t[ci*320 + k*64 + co] = conv2_w[i];
    }
    // w3t[ci*192 + k*64 + co] = conv3_w[co][ci][k]
    for (int i = tid; i < 64*64*3; i += stride) {
        int co = i / 192; int r = i - co*192; int ci = r / 3; int k = r - ci*3;
        w3t[ci*192 + k*64 + co] = conv3_w[i];
    }
    if (tid < 128) {
        float s = g1[tid] / sqrtf(v1[tid] + 1e-5f);
        so1[tid]       = s;
        so1[128 + tid] = (conv1_b[tid] - m1[tid]) * s + b1[tid];
    }
    if (tid < 64) {
        float s2 = g2[tid] / sqrtf(v2[tid] + 1e-5f);
        so2[tid]      = s2;
        so2[64 + tid] = (conv2_b[tid] - m2[tid]) * s2 + b2[tid];
        float s3 = g3[tid] / sqrtf(v3[tid] + 1e-5f);
        so3[tid]      = s3;
        so3[64 + tid] = (conv3_b[tid] - m3[tid]) * s3 + b3[tid];
    }
}

// ---------------- fused conv1+bn1+pool+relu -> conv2+bn2+pool+relu ----------------
// block = (batch b, tile of TP2 pooled conv2 outputs). h1 recomputed per tile in LDS.
__launch_bounds__(256)
__global__ void conv12_kernel(
    const float* __restrict__ x, const float* __restrict__ w1,
    const float* __restrict__ w2t, const float* __restrict__ so1,
    const float* __restrict__ so2, float* __restrict__ h2)
{
    __shared__ float xl[3][XT];
    __shared__ float h1l[128][P1];
    __shared__ float w1l[1152];
    __shared__ float s1l[128], o1l[128];

    int t  = threadIdx.x;
    int b  = blockIdx.x;
    int u0 = blockIdx.y * TP2;   // pooled conv2 output start
    int q0 = 3 * u0;             // h1 start
    int x0 = 2 * q0;             // x start

    // stage x tile (clamped at tail; garbage h1 beyond valid range is never stored)
    for (int i = t; i < 3 * XT; i += 256) {
        int c = i / XT, p = i - c * XT;
        int gp = x0 + p; if (gp > SIGLEN - 1) gp = SIGLEN - 1;
        xl[c][p] = x[(b * 3 + c) * SIGLEN + gp];
    }
    for (int i = t; i < 1152; i += 256) w1l[i] = w1[i];
    if (t < 128) { s1l[t] = so1[t]; o1l[t] = so1[128 + t]; }
    __syncthreads();

    // stage 1: h1 tile = relu(s1*maxpool(conv1)+o1), 128ch x P1 pos
    for (int i = t; i < 128 * P1; i += 256) {
        int ch = i / P1, q = i - ch * P1;
        const float* wp = &w1l[ch * 9];
        float r0 = 0.f, r1 = 0.f, r2 = 0.f;
        #pragma unroll
        for (int ci = 0; ci < 3; ++ci) {
            float v0 = xl[ci][2*q+0], va = xl[ci][2*q+1], vb = xl[ci][2*q+2];
            float vc = xl[ci][2*q+3], vd = xl[ci][2*q+4];
            float wA = wp[ci*3+0], wB = wp[ci*3+1], wC = wp[ci*3+2];
            r0 += v0*wA + va*wB + vb*wC;
            r1 += va*wA + vb*wB + vc*wC;
            r2 += vb*wA + vc*wB + vd*wC;
        }
        float m = fmaxf(r0, fmaxf(r1, r2));
        h1l[ch][q] = fmaxf(s1l[ch] * m + o1l[ch], 0.f);
    }
    __syncthreads();

    // stage 2: conv2. thread = 4 co x 6 conv positions
    int co0 = (t & 15) * 4;
    int p0  = (t >> 4) * 6;
    float acc[4][6];
    #pragma unroll
    for (int c = 0; c < 4; ++c)
        #pragma unroll
        for (int j = 0; j < 6; ++j) acc[c][j] = 0.f;

    for (int ci = 0; ci < 128; ++ci) {
        float hv[10];
        #pragma unroll
        for (int j = 0; j < 10; ++j) hv[j] = h1l[ci][p0 + j];
        const float* wp = &w2t[ci * 320 + co0];
        #pragma unroll
        for (int k = 0; k < 5; ++k) {
            float4 wv = *(const float4*)(wp + k * 64);
            #pragma unroll
            for (int j = 0; j < 6; ++j) {
                float h = hv[j + k];
                acc[0][j] += h * wv.x;
                acc[1][j] += h * wv.y;
                acc[2][j] += h * wv.z;
                acc[3][j] += h * wv.w;
            }
        }
    }
    // pool(3,3) + bn2 + relu; each thread owns 2 pooled outputs x 4 co
    #pragma unroll
    for (int c = 0; c < 4; ++c) {
        int co = co0 + c;
        float s = so2[co], o = so2[64 + co];
        #pragma unroll
        for (int ul = 0; ul < 2; ++ul) {
            int u = u0 + (p0 / 3) + ul;
            if (u < L2OUT) {
                float m = fmaxf(acc[c][3*ul], fmaxf(acc[c][3*ul+1], acc[c][3*ul+2]));
                h2[(b * 64 + co) * L2OUT + u] = fmaxf(s * m + o, 0.f);
            }
        }
    }
}

// ---------------- conv3+bn3+pool+relu -> flattened xs ----------------
// block = batch. h2[b] + transposed weights in LDS.
__launch_bounds__(256)
__global__ void conv3_kernel(
    const float* __restrict__ h2, const float* __restrict__ w3t,
    const float* __restrict__ so3, float* __restrict__ xs)
{
    __shared__ float h2l[64][344];   // 339 padded
    __shared__ float w3l[64 * 192];
    int b = blockIdx.x;
    int t = threadIdx.x;
    for (int i = t; i < 64 * L2OUT; i += 256) {
        int ci = i / L2OUT, p = i - ci * L2OUT;
        h2l[ci][p] = h2[(b * 64 + ci) * L2OUT + p];
    }
    for (int i = t; i < 64 * 192; i += 256) w3l[i] = w3t[i];
    __syncthreads();

    int co0 = (t & 15) * 4;
    int tu  = t >> 4;  // 0..15
    float s[4], o[4];
    #pragma unroll
    for (int c = 0; c < 4; ++c) { s[c] = so3[co0 + c]; o[c] = so3[64 + co0 + c]; }

    for (int uu = 0; uu < 11; ++uu) {
        int u = tu * 11 + uu;
        if (u < L3OUT) {
            float acc[4][3];
            #pragma unroll
            for (int c = 0; c < 4; ++c)
                #pragma unroll
                for (int p = 0; p < 3; ++p) acc[c][p] = 0.f;
            for (int ci = 0; ci < 64; ++ci) {
                float hv[5];
                #pragma unroll
                for (int j = 0; j < 5; ++j) hv[j] = h2l[ci][2 * u + j];
                const float* wp = &w3l[ci * 192 + co0];
                #pragma unroll
                for (int k = 0; k < 3; ++k) {
                    float4 wv = *(const float4*)(wp + k * 64);
                    #pragma unroll
                    for (int p = 0; p < 3; ++p) {
                        float h = hv[p + k];
                        acc[0][p] += h * wv.x;
                        acc[1][p] += h * wv.y;
                        acc[2][p] += h * wv.z;
                        acc[3][p] += h * wv.w;
                    }
                }
            }
            #pragma unroll
            for (int c = 0; c < 4; ++c) {
                float m = fmaxf(acc[c][0], fmaxf(acc[c][1], acc[c][2]));
                xs[b * FCIN + (co0 + c) * L3OUT + u] = fmaxf(s[c] * m + o[c], 0.f);
            }
        }
    }
}

// ---------------- fc1 (10752 -> 48) + relu ----------------
// block = 4 batches; wave w handles 12 outputs; lane-strided K, butterfly reduce.
__launch_bounds__(256)
__global__ void fc1_kernel(
    const float* __restrict__ xs, const float* __restrict__ w,
    const float* __restrict__ bias, float* __restrict__ xs1)
{
    int t = threadIdx.x, lane = t & 63, wid = t >> 6;
    int b0 = blockIdx.x * 4;
    int o0 = wid * 12;
    float acc[48];
    #pragma unroll
    for (int i = 0; i < 48; ++i) acc[i] = 0.f;

    for (int k = lane; k < FCIN; k += 64) {
        float xv0 = xs[(b0 + 0) * FCIN + k];
        float xv1 = xs[(b0 + 1) * FCIN + k];
        float xv2 = xs[(b0 + 2) * FCIN + k];
        float xv3 = xs[(b0 + 3) * FCIN + k];
        #pragma unroll
        for (int j = 0; j < 12; ++j) {
            float ww = w[(o0 + j) * FCIN + k];
            acc[j]      += xv0 * ww;
            acc[12 + j] += xv1 * ww;
            acc[24 + j] += xv2 * ww;
            acc[36 + j] += xv3 * ww;
        }
    }
    #pragma unroll
    for (int i = 0; i < 48; ++i) {
        #pragma unroll
        for (int off = 32; off > 0; off >>= 1)
            acc[i] += __shfl_xor(acc[i], off, 64);
    }
    if (lane == 0) {
        #pragma unroll
        for (int bb = 0; bb < 4; ++bb)
            #pragma unroll
            for (int j = 0; j < 12; ++j)
                xs1[(b0 + bb) * 48 + o0 + j] = fmaxf(acc[bb * 12 + j] + bias[o0 + j], 0.f);
    }
}

// ---------------- fc2/fc3/fc4 + tanh + A = basis @ theta ----------------
// single block; thread = batch.
__launch_bounds__(256)
__global__ void fc234_kernel(
    const float* __restrict__ xs1,
    const float* __restrict__ fc2_w, const float* __restrict__ fc2_b,
    const float* __restrict__ fc3_w, const float* __restrict__ fc3_b,
    const float* __restrict__ fc4_w, const float* __restrict__ fc4_b,
    const float* __restrict__ basis, float* __restrict__ A)
{
    __shared__ float xsl[256 * 49];  // padded stride 49 (conflict-free)
    __shared__ float w2l[1536], w3l[512], w4l[80];
    __shared__ float b2l[32], b3l[16], b4l[8], basl[60];
    int t = threadIdx.x;
    for (int i = t; i < 256 * 48; i += 256) xsl[(i / 48) * 49 + (i % 48)] = xs1[i];
    for (int i = t; i < 1536; i += 256) w2l[i] = fc2_w[i];
    for (int i = t; i < 512;  i += 256) w3l[i] = fc3_w[i];
    if (t < 80) w4l[t] = fc4_w[t];
    if (t < 32) b2l[t] = fc2_b[t];
    if (t < 16) b3l[t] = fc3_b[t];
    if (t < 5)  b4l[t] = fc4_b[t];
    if (t < 60) basl[t] = basis[t];
    __syncthreads();

    const float* xin = &xsl[t * 49];
    float h[32];
    #pragma unroll 4
    for (int o = 0; o < 32; ++o) {
        float sv = b2l[o];
        for (int i = 0; i < 48; ++i) sv += w2l[o * 48 + i] * xin[i];
        h[o] = fmaxf(sv, 0.f);
    }
    float g[16];
    #pragma unroll 4
    for (int o = 0; o < 16; ++o) {
        float sv = b3l[o];
        for (int i = 0; i < 32; ++i) sv += w3l[o * 32 + i] * h[i];
        g[o] = fmaxf(sv, 0.f);
    }
    float th[5];
    #pragma unroll
    for (int o = 0; o < 5; ++o) {
        float sv = b4l[o];
        for (int i = 0; i < 16; ++i) sv += w4l[o * 16 + i] * g[i];
        th[o] = tanhf(sv);
    }
    #pragma unroll
    for (int j = 0; j < 12; ++j) {
        float sv = 0.f;
        #pragma unroll
        for (int d = 0; d < 5; ++d) sv += basl[j * 5 + d] * th[d];
        A[t * 12 + j] = sv;
    }
}

// ---------------- CPAB integrate (7 iters) + interp + transpose ----------------
__launch_bounds__(256)
__global__ void warp_kernel(
    const float* __restrict__ x, const float* __restrict__ A,
    float* __restrict__ out)
{
    __shared__ float Al[12];
    int b = blockIdx.x;
    int i = blockIdx.y * 256 + threadIdx.x;  // 0..2047
    if (threadIdx.x < 12) Al[threadIdx.x] = A[b * 12 + threadIdx.x];
    __syncthreads();

    float xp = (float)i / 2047.f;
    float t  = 1.f;
    for (int it = 0; it < 7; ++it) {
        int c = (int)floorf(xp * 6.f);
        c = min(max(c, 0), 5);
        float a  = Al[2 * c], bb = Al[2 * c + 1];
        float v  = a * xp + bb;
        float xb = (v >= 0.f) ? (float)(c + 1) / 6.f : (float)c / 6.f;
        bool  big_a = fabsf(a) > 1e-8f;
        float a_s = big_a ? a : 1.f;
        float z   = xp + bb / a_s;
        float zb  = xb + bb / a_s;
        float zden = (fabsf(z) > 1e-12f) ? z : 1e-12f;
        float ratio = zb / zden;
        float t_exp = logf(fmaxf(ratio, 1e-12f)) / a_s;
        float v_s   = (fabsf(v) > 1e-12f) ? v : 1.f;
        float t_lin = (xb - xp) / v_s;
        float thit  = big_a ? t_exp : t_lin;
        bool valid  = (fabsf(v) > 1e-12f) && (thit > 0.f) && ((big_a ? ratio : 1.f) > 0.f);
        if (!valid) thit = __builtin_inff();
        float tau   = fminf(t, thit);
        float x_new = big_a ? (z * expf(a * tau) - (z - xp)) : (xp + bb * tau);
        bool hit    = (thit <= t);
        float nudge = (v >= 0.f) ? 1e-6f : -1e-6f;
        xp = hit ? (xb + nudge) : x_new;
        xp = fminf(fmaxf(xp, 0.f), 1.f);
        t  = fmaxf(t - tau, 0.f);
    }
    float p = fminf(fmaxf(xp, 0.f), 1.f) * 2047.f;
    int i0 = (int)floorf(p);
    i0 = min(max(i0, 0), 2046);
    float w = p - (float)i0;
    #pragma unroll
    for (int c = 0; c < 3; ++c) {
        const float* d = &x[(b * 3 + c) * SIGLEN];
        out[(b * 3 + c) * SIGLEN + i] = d[i0] * (1.f - w) + d[i0 + 1] * w;
    }
}

// ---------------- launch ----------------
extern "C" void kernel_launch(void* const* d_in, const int* in_sizes, int n_in,
                              void* d_out, int out_size, void* d_ws, size_t ws_size,
                              hipStream_t stream) {
    (void)in_sizes; (void)n_in; (void)out_size; (void)ws_size;
    const float* x       = (const float*)d_in[0];
    const float* conv1_w = (const float*)d_in[1];
    const float* conv1_b = (const float*)d_in[2];
    const float* bn1_g   = (const float*)d_in[3];
    const float* bn1_b   = (const float*)d_in[4];
    const float* bn1_m   = (const float*)d_in[5];
    const float* bn1_v   = (const float*)d_in[6];
    const float* conv2_w = (const float*)d_in[7];
    const float* conv2_b = (const float*)d_in[8];
    const float* bn2_g   = (const float*)d_in[9];
    const float* bn2_b   = (const float*)d_in[10];
    const float* bn2_m   = (const float*)d_in[11];
    const float* bn2_v   = (const float*)d_in[12];
    const float* conv3_w = (const float*)d_in[13];
    const float* conv3_b = (const float*)d_in[14];
    const float* bn3_g   = (const float*)d_in[15];
    const float* bn3_b   = (const float*)d_in[16];
    const float* bn3_m   = (const float*)d_in[17];
    const float* bn3_v   = (const float*)d_in[18];
    const float* fc1_w   = (const float*)d_in[19];
    const float* fc1_b   = (const float*)d_in[20];
    const float* fc2_w   = (const float*)d_in[21];
    const float* fc2_b   = (const float*)d_in[22];
    const float* fc3_w   = (const float*)d_in[23];
    const float* fc3_b   = (const float*)d_in[24];
    const float* fc4_w   = (const float*)d_in[25];
    const float* fc4_b   = (const float*)d_in[26];
    const float* basis   = (const float*)d_in[27];

    float* ws  = (float*)d_ws;
    float* w2t = ws;                    // 40960
    float* w3t = w2t + 40960;           // 12288
    float* so1 = w3t + 12288;           // 256
    float* so2 = so1 + 256;             // 128
    float* so3 = so2 + 128;             // 128
    float* h2  = so3 + 128;             // 256*64*339 = 5554176
    float* xs  = h2  + 5554176;         // 256*10752  = 2752512
    float* xs1 = xs  + 2752512;         // 256*48     = 12288
    float* Aws = xs1 + 12288;           // 256*12     = 3072
    // total ~8.38M floats = 33.5 MB

    prep_kernel<<<64, 256, 0, stream>>>(
        conv1_b, bn1_g, bn1_b, bn1_m, bn1_v,
        conv2_w, conv2_b, bn2_g, bn2_b, bn2_m, bn2_v,
        conv3_w, conv3_b, bn3_g, bn3_b, bn3_m, bn3_v,
        w2t, w3t, so1, so2, so3);

    dim3 g2(BATCH, (L2OUT + TP2 - 1) / TP2);  // (256, 11)
    conv12_kernel<<<g2, 256, 0, stream>>>(x, conv1_w, w2t, so1, so2, h2);

    conv3_kernel<<<BATCH, 256, 0, stream>>>(h2, w3t, so3, xs);

    fc1_kernel<<<BATCH / 4, 256, 0, stream>>>(xs, fc1_w, fc1_b, xs1);

    fc234_kernel<<<1, 256, 0, stream>>>(xs1, fc2_w, fc2_b, fc3_w, fc3_b,
                                        fc4_w, fc4_b, basis, Aws);

    dim3 g5(BATCH, SIGLEN / 256);  // (256, 8)
    warp_kernel<<<g5, 256, 0, stream>>>(x, Aws, (float*)d_out);
}

// Round 2
// 492.017 us; speedup vs baseline: 1.2896x; 1.2896x over previous
//
#include <hip/hip_runtime.h>
#include <math.h>

// ---------------- problem constants ----------------
#define BATCH   256
#define SIGLEN  2048
#define L1OUT   1022   // conv1(2046) -> pool k3 s2
#define L2OUT   339    // conv2(1018) -> pool k3 s3
#define L3OUT   168    // conv3(337)  -> pool k3 s2
#define FCIN    10752  // 64*168

// conv12 tiling: block = (batch, 21 pooled outputs) -> 63 conv2 positions,
// 4 waves x 16-position MFMA tiles (64 pos incl. slack), 68 h1 rows (+4 halo)
#define TP2      21
#define NROW     68
#define H1STRIDE 132   // 132*2B = 264B rows: 8B-aligned b64 frag reads, benign banks

typedef float f32x4 __attribute__((ext_vector_type(4)));
typedef short s16x8 __attribute__((ext_vector_type(8)));
typedef short s16x4 __attribute__((ext_vector_type(4)));

__device__ __forceinline__ unsigned short f2bf(float f) {
    unsigned int u = __float_as_uint(f);
    return (unsigned short)((u + 0x7fffu + ((u >> 16) & 1u)) >> 16);
}
__device__ __forceinline__ float bf2f(unsigned short h) {
    return __uint_as_float(((unsigned int)h) << 16);
}

// ---------------- prep: W2 hi/lo bf16 fragments + w3 transpose + BN fold ----------------
__launch_bounds__(256)
__global__ void prep_kernel(
    const float* __restrict__ conv1_b,
    const float* __restrict__ g1, const float* __restrict__ b1,
    const float* __restrict__ m1, const float* __restrict__ v1,
    const float* __restrict__ conv2_w, const float* __restrict__ conv2_b,
    const float* __restrict__ g2, const float* __restrict__ b2,
    const float* __restrict__ m2, const float* __restrict__ v2,
    const float* __restrict__ conv3_w, const float* __restrict__ conv3_b,
    const float* __restrict__ g3, const float* __restrict__ b3,
    const float* __restrict__ m3, const float* __restrict__ v3,
    unsigned short* __restrict__ w2hi, unsigned short* __restrict__ w2lo,
    float* __restrict__ w3t,
    float* __restrict__ so1, float* __restrict__ so2, float* __restrict__ so3)
{
    int tid = blockIdx.x * 256 + threadIdx.x;
    int stride = gridDim.x * 256;
    // W2 fragment layout: [(k*4 + ci>>5)*64 + co]*32 + (ci&31), split hi/lo bf16
    for (int i = tid; i < 64*128*5; i += stride) {
        int co = i / 640; int rr = i - co*640; int ci = rr / 5; int k = rr - ci*5;
        float w = conv2_w[i];
        unsigned short hi = f2bf(w);
        unsigned short lo = f2bf(w - bf2f(hi));
        int dst = ((k*4 + (ci >> 5))*64 + co)*32 + (ci & 31);
        w2hi[dst] = hi;
        w2lo[dst] = lo;
    }
    // w3t[ci*192 + k*64 + co] = conv3_w[co][ci][k]
    for (int i = tid; i < 64*64*3; i += stride) {
        int co = i / 192; int r = i - co*192; int ci = r / 3; int k = r - ci*3;
        w3t[ci*192 + k*64 + co] = conv3_w[i];
    }
    if (tid < 128) {
        float s = g1[tid] / sqrtf(v1[tid] + 1e-5f);
        so1[tid]       = s;
        so1[128 + tid] = (conv1_b[tid] - m1[tid]) * s + b1[tid];
    }
    if (tid < 64) {
        float s2 = g2[tid] / sqrtf(v2[tid] + 1e-5f);
        so2[tid]      = s2;
        so2[64 + tid] = (conv2_b[tid] - m2[tid]) * s2 + b2[tid];
        float s3 = g3[tid] / sqrtf(v3[tid] + 1e-5f);
        so3[tid]      = s3;
        so3[64 + tid] = (conv3_b[tid] - m3[tid]) * s3 + b3[tid];
    }
}

// ---------------- fused conv1(+bn+pool+relu, fp32) -> conv2 via split-bf16 MFMA ----------------
// Stage 1: h1 rows q0..q0+67 computed on VALU, wave-uniform row (x loads scalarize),
//          stored as separate hi/lo bf16 LDS arrays (row stride 132).
// Stage 2: wave w = 16-pos tile (w*16..+15), all 64 co (4 co-tiles), K = 5 shifts x 4 ci-blocks.
//          A (h1) frags from LDS, B (W2) frags from global (L1/L2-cached), 3 MFMA per pair.
// Epilogue: D -> LDS c2[64pos][65] -> pool(3,3)+bn2+relu -> h2[b][u][co] coalesced.
__launch_bounds__(256, 3)
__global__ void conv12_kernel(
    const float* __restrict__ x, const float* __restrict__ w1,
    const unsigned short* __restrict__ w2hi, const unsigned short* __restrict__ w2lo,
    const float* __restrict__ so1, const float* __restrict__ so2,
    float* __restrict__ h2)
{
    __shared__ unsigned short h1hi[NROW * H1STRIDE];
    __shared__ unsigned short h1lo[NROW * H1STRIDE];
    __shared__ float c2[64 * 65];

    int t  = threadIdx.x;
    int b  = blockIdx.x;
    int u0 = blockIdx.y * TP2;
    int q0 = 3 * u0;
    int wv = __builtin_amdgcn_readfirstlane(t >> 6);  // wave id, SGPR
    int l  = t & 63;

    // ---- stage 1: conv1 + bn1 + pool + relu, bf16 hi/lo split ----
    float wr[2][9];
    float s1r[2], o1r[2];
    #pragma unroll
    for (int h = 0; h < 2; ++h) {
        int ch = l + 64*h;
        #pragma unroll
        for (int j = 0; j < 9; ++j) wr[h][j] = w1[ch*9 + j];
        s1r[h] = so1[ch]; o1r[h] = so1[128 + ch];
    }
    for (int s = 0; s < 17; ++s) {
        int r = 4*s + wv;              // local h1 row, wave-uniform
        int xbase = 2*(q0 + r);
        float xv[3][5];
        #pragma unroll
        for (int ci = 0; ci < 3; ++ci) {
            const float* xp = x + (b*3 + ci)*SIGLEN;
            #pragma unroll
            for (int d = 0; d < 5; ++d) {
                int xi = xbase + d; xi = xi < SIGLEN ? xi : SIGLEN - 1;
                xv[ci][d] = xp[xi];
            }
        }
        #pragma unroll
        for (int h = 0; h < 2; ++h) {
            float r0 = 0.f, r1 = 0.f, r2 = 0.f;
            #pragma unroll
            for (int ci = 0; ci < 3; ++ci) {
                float wA = wr[h][ci*3], wB = wr[h][ci*3+1], wC = wr[h][ci*3+2];
                r0 = fmaf(xv[ci][0], wA, fmaf(xv[ci][1], wB, fmaf(xv[ci][2], wC, r0)));
                r1 = fmaf(xv[ci][1], wA, fmaf(xv[ci][2], wB, fmaf(xv[ci][3], wC, r1)));
                r2 = fmaf(xv[ci][2], wA, fmaf(xv[ci][3], wB, fmaf(xv[ci][4], wC, r2)));
            }
            float mx = fmaxf(r0, fmaxf(r1, r2));
            float v  = fmaxf(fmaf(s1r[h], mx, o1r[h]), 0.f);
            unsigned short hi = f2bf(v);
            unsigned short lo = f2bf(v - bf2f(hi));
            h1hi[r*H1STRIDE + l + 64*h] = hi;
            h1lo[r*H1STRIDE + l + 64*h] = lo;
        }
    }
    __syncthreads();

    // ---- stage 2: MFMA GEMM ----
    int m  = l & 15;       // pos within tile (A) / co within tile (B)
    int qd = l >> 4;       // quad: k-segment selector
    f32x4 acc[4] = {(f32x4)(0.f), (f32x4)(0.f), (f32x4)(0.f), (f32x4)(0.f)};

    const unsigned short* whibase = w2hi + m*32 + qd*8;
    const unsigned short* wlobase = w2lo + m*32 + qd*8;

    for (int k = 0; k < 5; ++k) {
        #pragma unroll
        for (int cb = 0; cb < 4; ++cb) {
            int st = k*4 + cb;
            // B frags: 4 co-tiles x (hi,lo), 16B each, from global (cached)
            s16x8 wh[4], wl[4];
            #pragma unroll
            for (int ct = 0; ct < 4; ++ct) {
                wh[ct] = *(const s16x8*)(whibase + st*2048 + ct*512);
                wl[ct] = *(const s16x8*)(wlobase + st*2048 + ct*512);
            }
            // A frags: h1 row (pos + k shift), 8 contiguous ci, via 2x b64
            int row = wv*16 + m + k;
            const s16x4* ph = (const s16x4*)&h1hi[row*H1STRIDE + cb*32 + qd*8];
            const s16x4* pl = (const s16x4*)&h1lo[row*H1STRIDE + cb*32 + qd*8];
            s16x4 h0 = ph[0], h1f = ph[1];
            s16x4 l0 = pl[0], l1f = pl[1];
            s16x8 ah = __builtin_shufflevector(h0, h1f, 0,1,2,3,4,5,6,7);
            s16x8 al = __builtin_shufflevector(l0, l1f, 0,1,2,3,4,5,6,7);
            #pragma unroll
            for (int ct = 0; ct < 4; ++ct) {
                acc[ct] = __builtin_amdgcn_mfma_f32_16x16x32_bf16(ah, wh[ct], acc[ct], 0, 0, 0);
                acc[ct] = __builtin_amdgcn_mfma_f32_16x16x32_bf16(al, wh[ct], acc[ct], 0, 0, 0);
                acc[ct] = __builtin_amdgcn_mfma_f32_16x16x32_bf16(ah, wl[ct], acc[ct], 0, 0, 0);
            }
        }
    }

    // D layout: row(pos) = qd*4+reg, col(co) = m
    #pragma unroll
    for (int ct = 0; ct < 4; ++ct)
        #pragma unroll
        for (int rg = 0; rg < 4; ++rg)
            c2[(wv*16 + qd*4 + rg)*65 + ct*16 + m] = acc[ct][rg];
    __syncthreads();

    // ---- pool(3,3) + bn2 + relu -> h2[b][u][co] (coalesced) ----
    #pragma unroll
    for (int it = 0; it < 6; ++it) {
        int idx = t + it*256;
        if (idx < TP2*64) {
            int ul = idx >> 6, co = idx & 63;
            int u = u0 + ul;
            if (u < L2OUT) {
                float v0 = c2[(3*ul  )*65 + co];
                float v1 = c2[(3*ul+1)*65 + co];
                float v2 = c2[(3*ul+2)*65 + co];
                float mm = fmaxf(v0, fmaxf(v1, v2));
                h2[(b*L2OUT + u)*64 + co] = fmaxf(fmaf(so2[co], mm, so2[64 + co]), 0.f);
            }
        }
    }
}

// ---------------- conv3+bn3+pool+relu -> flattened xs ----------------
// h2 is now [b][u][co]; stage transposed into LDS (pad 345 breaks write conflicts).
__launch_bounds__(256)
__global__ void conv3_kernel(
    const float* __restrict__ h2, const float* __restrict__ w3t,
    const float* __restrict__ so3, float* __restrict__ xs)
{
    __shared__ float h2l[64 * 345];
    __shared__ float w3l[64 * 192];
    int b = blockIdx.x;
    int t = threadIdx.x;
    for (int i = t; i < 64 * L2OUT; i += 256) {
        int p = i >> 6, ci = i & 63;
        h2l[ci*345 + p] = h2[(b*L2OUT + p)*64 + ci];
    }
    for (int i = t; i < 64 * 192; i += 256) w3l[i] = w3t[i];
    __syncthreads();

    int co0 = (t & 15) * 4;
    int tu  = t >> 4;  // 0..15
    float s[4], o[4];
    #pragma unroll
    for (int c = 0; c < 4; ++c) { s[c] = so3[co0 + c]; o[c] = so3[64 + co0 + c]; }

    for (int uu = 0; uu < 11; ++uu) {
        int u = tu * 11 + uu;
        if (u < L3OUT) {
            float acc[4][3];
            #pragma unroll
            for (int c = 0; c < 4; ++c)
                #pragma unroll
                for (int p = 0; p < 3; ++p) acc[c][p] = 0.f;
            for (int ci = 0; ci < 64; ++ci) {
                float hv[5];
                #pragma unroll
                for (int j = 0; j < 5; ++j) hv[j] = h2l[ci*345 + 2*u + j];
                const float* wp = &w3l[ci * 192 + co0];
                #pragma unroll
                for (int k = 0; k < 3; ++k) {
                    float4 wv = *(const float4*)(wp + k * 64);
                    #pragma unroll
                    for (int p = 0; p < 3; ++p) {
                        float h = hv[p + k];
                        acc[0][p] += h * wv.x;
                        acc[1][p] += h * wv.y;
                        acc[2][p] += h * wv.z;
                        acc[3][p] += h * wv.w;
                    }
                }
            }
            #pragma unroll
            for (int c = 0; c < 4; ++c) {
                float mm = fmaxf(acc[c][0], fmaxf(acc[c][1], acc[c][2]));
                xs[b * FCIN + (co0 + c) * L3OUT + u] = fmaxf(s[c] * mm + o[c], 0.f);
            }
        }
    }
}

// ---------------- fc1 (10752 -> 48) + relu ----------------
__launch_bounds__(256)
__global__ void fc1_kernel(
    const float* __restrict__ xs, const float* __restrict__ w,
    const float* __restrict__ bias, float* __restrict__ xs1)
{
    int t = threadIdx.x, lane = t & 63, wid = t >> 6;
    int b0 = blockIdx.x * 4;
    int o0 = wid * 12;
    float acc[48];
    #pragma unroll
    for (int i = 0; i < 48; ++i) acc[i] = 0.f;

    for (int k = lane; k < FCIN; k += 64) {
        float xv0 = xs[(b0 + 0) * FCIN + k];
        float xv1 = xs[(b0 + 1) * FCIN + k];
        float xv2 = xs[(b0 + 2) * FCIN + k];
        float xv3 = xs[(b0 + 3) * FCIN + k];
        #pragma unroll
        for (int j = 0; j < 12; ++j) {
            float ww = w[(o0 + j) * FCIN + k];
            acc[j]      += xv0 * ww;
            acc[12 + j] += xv1 * ww;
            acc[24 + j] += xv2 * ww;
            acc[36 + j] += xv3 * ww;
        }
    }
    #pragma unroll
    for (int i = 0; i < 48; ++i) {
        #pragma unroll
        for (int off = 32; off > 0; off >>= 1)
            acc[i] += __shfl_xor(acc[i], off, 64);
    }
    if (lane == 0) {
        #pragma unroll
        for (int bb = 0; bb < 4; ++bb)
            #pragma unroll
            for (int j = 0; j < 12; ++j)
                xs1[(b0 + bb) * 48 + o0 + j] = fmaxf(acc[bb * 12 + j] + bias[o0 + j], 0.f);
    }
}

// ---------------- fc2/fc3/fc4 + tanh + A = basis @ theta ----------------
__launch_bounds__(256)
__global__ void fc234_kernel(
    const float* __restrict__ xs1,
    const float* __restrict__ fc2_w, const float* __restrict__ fc2_b,
    const float* __restrict__ fc3_w, const float* __restrict__ fc3_b,
    const float* __restrict__ fc4_w, const float* __restrict__ fc4_b,
    const float* __restrict__ basis, float* __restrict__ A)
{
    __shared__ float xsl[256 * 49];
    __shared__ float w2l[1536], w3l[512], w4l[80];
    __shared__ float b2l[32], b3l[16], b4l[8], basl[60];
    int t = threadIdx.x;
    for (int i = t; i < 256 * 48; i += 256) xsl[(i / 48) * 49 + (i % 48)] = xs1[i];
    for (int i = t; i < 1536; i += 256) w2l[i] = fc2_w[i];
    for (int i = t; i < 512;  i += 256) w3l[i] = fc3_w[i];
    if (t < 80) w4l[t] = fc4_w[t];
    if (t < 32) b2l[t] = fc2_b[t];
    if (t < 16) b3l[t] = fc3_b[t];
    if (t < 5)  b4l[t] = fc4_b[t];
    if (t < 60) basl[t] = basis[t];
    __syncthreads();

    const float* xin = &xsl[t * 49];
    float h[32];
    #pragma unroll 4
    for (int o = 0; o < 32; ++o) {
        float sv = b2l[o];
        for (int i = 0; i < 48; ++i) sv += w2l[o * 48 + i] * xin[i];
        h[o] = fmaxf(sv, 0.f);
    }
    float g[16];
    #pragma unroll 4
    for (int o = 0; o < 16; ++o) {
        float sv = b3l[o];
        for (int i = 0; i < 32; ++i) sv += w3l[o * 32 + i] * h[i];
        g[o] = fmaxf(sv, 0.f);
    }
    float th[5];
    #pragma unroll
    for (int o = 0; o < 5; ++o) {
        float sv = b4l[o];
        for (int i = 0; i < 16; ++i) sv += w4l[o * 16 + i] * g[i];
        th[o] = tanhf(sv);
    }
    #pragma unroll
    for (int j = 0; j < 12; ++j) {
        float sv = 0.f;
        #pragma unroll
        for (int d = 0; d < 5; ++d) sv += basl[j * 5 + d] * th[d];
        A[t * 12 + j] = sv;
    }
}

// ---------------- CPAB integrate (7 iters) + interp + transpose ----------------
__launch_bounds__(256)
__global__ void warp_kernel(
    const float* __restrict__ x, const float* __restrict__ A,
    float* __restrict__ out)
{
    __shared__ float Al[12];
    int b = blockIdx.x;
    int i = blockIdx.y * 256 + threadIdx.x;  // 0..2047
    if (threadIdx.x < 12) Al[threadIdx.x] = A[b * 12 + threadIdx.x];
    __syncthreads();

    float xp = (float)i / 2047.f;
    float t  = 1.f;
    for (int it = 0; it < 7; ++it) {
        int c = (int)floorf(xp * 6.f);
        c = min(max(c, 0), 5);
        float a  = Al[2 * c], bb = Al[2 * c + 1];
        float v  = a * xp + bb;
        float xb = (v >= 0.f) ? (float)(c + 1) / 6.f : (float)c / 6.f;
        bool  big_a = fabsf(a) > 1e-8f;
        float a_s = big_a ? a : 1.f;
        float z   = xp + bb / a_s;
        float zb  = xb + bb / a_s;
        float zden = (fabsf(z) > 1e-12f) ? z : 1e-12f;
        float ratio = zb / zden;
        float t_exp = logf(fmaxf(ratio, 1e-12f)) / a_s;
        float v_s   = (fabsf(v) > 1e-12f) ? v : 1.f;
        float t_lin = (xb - xp) / v_s;
        float thit  = big_a ? t_exp : t_lin;
        bool valid  = (fabsf(v) > 1e-12f) && (thit > 0.f) && ((big_a ? ratio : 1.f) > 0.f);
        if (!valid) thit = __builtin_inff();
        float tau   = fminf(t, thit);
        float x_new = big_a ? (z * expf(a * tau) - (z - xp)) : (xp + bb * tau);
        bool hit    = (thit <= t);
        float nudge = (v >= 0.f) ? 1e-6f : -1e-6f;
        xp = hit ? (xb + nudge) : x_new;
        xp = fminf(fmaxf(xp, 0.f), 1.f);
        t  = fmaxf(t - tau, 0.f);
    }
    float p = fminf(fmaxf(xp, 0.f), 1.f) * 2047.f;
    int i0 = (int)floorf(p);
    i0 = min(max(i0, 0), 2046);
    float w = p - (float)i0;
    #pragma unroll
    for (int c = 0; c < 3; ++c) {
        const float* d = &x[(b * 3 + c) * SIGLEN];
        out[(b * 3 + c) * SIGLEN + i] = d[i0] * (1.f - w) + d[i0 + 1] * w;
    }
}

// ---------------- launch ----------------
extern "C" void kernel_launch(void* const* d_in, const int* in_sizes, int n_in,
                              void* d_out, int out_size, void* d_ws, size_t ws_size,
                              hipStream_t stream) {
    (void)in_sizes; (void)n_in; (void)out_size; (void)ws_size;
    const float* x       = (const float*)d_in[0];
    const float* conv1_w = (const float*)d_in[1];
    const float* conv1_b = (const float*)d_in[2];
    const float* bn1_g   = (const float*)d_in[3];
    const float* bn1_b   = (const float*)d_in[4];
    const float* bn1_m   = (const float*)d_in[5];
    const float* bn1_v   = (const float*)d_in[6];
    const float* conv2_w = (const float*)d_in[7];
    const float* conv2_b = (const float*)d_in[8];
    const float* bn2_g   = (const float*)d_in[9];
    const float* bn2_b   = (const float*)d_in[10];
    const float* bn2_m   = (const float*)d_in[11];
    const float* bn2_v   = (const float*)d_in[12];
    const float* conv3_w = (const float*)d_in[13];
    const float* conv3_b = (const float*)d_in[14];
    const float* bn3_g   = (const float*)d_in[15];
    const float* bn3_b   = (const float*)d_in[16];
    const float* bn3_m   = (const float*)d_in[17];
    const float* bn3_v   = (const float*)d_in[18];
    const float* fc1_w   = (const float*)d_in[19];
    const float* fc1_b   = (const float*)d_in[20];
    const float* fc2_w   = (const float*)d_in[21];
    const float* fc2_b   = (const float*)d_in[22];
    const float* fc3_w   = (const float*)d_in[23];
    const float* fc3_b   = (const float*)d_in[24];
    const float* fc4_w   = (const float*)d_in[25];
    const float* fc4_b   = (const float*)d_in[26];
    const float* basis   = (const float*)d_in[27];

    // workspace layout
    unsigned short* w2hi = (unsigned short*)d_ws;     // 40960 ushort
    unsigned short* w2lo = w2hi + 40960;              // 40960 ushort
    float* ws  = (float*)d_ws;
    float* w3t = ws + 40960;            // 163840B consumed above = 40960 floats
    float* so1 = w3t + 12288;
    float* so2 = so1 + 256;
    float* so3 = so2 + 128;
    float* h2  = so3 + 128;             // 256*339*64 = 5554176 (layout [b][u][co])
    float* xs  = h2  + 5554176;         // 256*10752
    float* xs1 = xs  + 2752512;         // 256*48
    float* Aws = xs1 + 12288;           // 256*12
    // total ~8.38M floats = 33.5 MB

    prep_kernel<<<64, 256, 0, stream>>>(
        conv1_b, bn1_g, bn1_b, bn1_m, bn1_v,
        conv2_w, conv2_b, bn2_g, bn2_b, bn2_m, bn2_v,
        conv3_w, conv3_b, bn3_g, bn3_b, bn3_m, bn3_v,
        w2hi, w2lo, w3t, so1, so2, so3);

    dim3 g2(BATCH, (L2OUT + TP2 - 1) / TP2);  // (256, 17)
    conv12_kernel<<<g2, 256, 0, stream>>>(x, conv1_w, w2hi, w2lo, so1, so2, h2);

    conv3_kernel<<<BATCH, 256, 0, stream>>>(h2, w3t, so3, xs);

    fc1_kernel<<<BATCH / 4, 256, 0, stream>>>(xs, fc1_w, fc1_b, xs1);

    fc234_kernel<<<1, 256, 0, stream>>>(xs1, fc2_w, fc2_b, fc3_w, fc3_b,
                                        fc4_w, fc4_b, basis, Aws);

    dim3 g5(BATCH, SIGLEN / 256);  // (256, 8)
    warp_kernel<<<g5, 256, 0, stream>>>(x, Aws, (float*)d_out);
}

// Round 3
// 331.958 us; speedup vs baseline: 1.9114x; 1.4822x over previous
//
#include <hip/hip_runtime.h>
#include <math.h>

// ---------------- problem constants ----------------
#define BATCH   256
#define SIGLEN  2048
#define L1OUT   1022   // conv1(2046) -> pool k3 s2
#define L2OUT   339    // conv2(1018) -> pool k3 s3
#define L3OUT   168    // conv3(337)  -> pool k3 s2
#define FCIN    10752  // 64*168

// conv12 tiling: block = (batch, 21 pooled outputs) -> 63 conv2 positions,
// wave w = co-tile w (16 co), iterates 4 position-tiles. 68 h1 rows incl halo.
#define TP2   21
#define NROW  68
#define H1S   136   // row stride (shorts): 272B rows, 16B-aligned -> ds_read_b128

typedef float f32x4 __attribute__((ext_vector_type(4)));
typedef short s16x8 __attribute__((ext_vector_type(8)));

__device__ __forceinline__ unsigned short f2bf(float f) {
    unsigned int u = __float_as_uint(f);
    return (unsigned short)((u + 0x7fffu + ((u >> 16) & 1u)) >> 16);
}
__device__ __forceinline__ float bf2f(unsigned short h) {
    return __uint_as_float(((unsigned int)h) << 16);
}

// ---------------- prep: W2 hi/lo bf16 fragments + w3 transpose + BN fold ----------------
__launch_bounds__(256)
__global__ void prep_kernel(
    const float* __restrict__ conv1_b,
    const float* __restrict__ g1, const float* __restrict__ b1,
    const float* __restrict__ m1, const float* __restrict__ v1,
    const float* __restrict__ conv2_w, const float* __restrict__ conv2_b,
    const float* __restrict__ g2, const float* __restrict__ b2,
    const float* __restrict__ m2, const float* __restrict__ v2,
    const float* __restrict__ conv3_w, const float* __restrict__ conv3_b,
    const float* __restrict__ g3, const float* __restrict__ b3,
    const float* __restrict__ m3, const float* __restrict__ v3,
    unsigned short* __restrict__ w2hi, unsigned short* __restrict__ w2lo,
    float* __restrict__ w3t,
    float* __restrict__ so1, float* __restrict__ so2, float* __restrict__ so3)
{
    int tid = blockIdx.x * 256 + threadIdx.x;
    int stride = gridDim.x * 256;
    // W2 fragment layout: [(k*4 + ci>>5)*64 + co]*32 + (ci&31), split hi/lo bf16
    for (int i = tid; i < 64*128*5; i += stride) {
        int co = i / 640; int rr = i - co*640; int ci = rr / 5; int k = rr - ci*5;
        float w = conv2_w[i];
        unsigned short hi = f2bf(w);
        unsigned short lo = f2bf(w - bf2f(hi));
        int dst = ((k*4 + (ci >> 5))*64 + co)*32 + (ci & 31);
        w2hi[dst] = hi;
        w2lo[dst] = lo;
    }
    // w3t[ci*192 + k*64 + co] = conv3_w[co][ci][k]
    for (int i = tid; i < 64*64*3; i += stride) {
        int co = i / 192; int r = i - co*192; int ci = r / 3; int k = r - ci*3;
        w3t[ci*192 + k*64 + co] = conv3_w[i];
    }
    if (tid < 128) {
        float s = g1[tid] / sqrtf(v1[tid] + 1e-5f);
        so1[tid]       = s;
        so1[128 + tid] = (conv1_b[tid] - m1[tid]) * s + b1[tid];
    }
    if (tid < 64) {
        float s2 = g2[tid] / sqrtf(v2[tid] + 1e-5f);
        so2[tid]      = s2;
        so2[64 + tid] = (conv2_b[tid] - m2[tid]) * s2 + b2[tid];
        float s3 = g3[tid] / sqrtf(v3[tid] + 1e-5f);
        so3[tid]      = s3;
        so3[64 + tid] = (conv3_b[tid] - m3[tid]) * s3 + b3[tid];
    }
}

// ---------------- fused conv1(+bn+pool+relu, fp32) -> conv2 via split-bf16 MFMA ----------------
// Wave w = co-tile w: loads ONLY its 16-co B frags from global (4x less L2 traffic),
// reads A frags for all 4 pos-tiles from LDS via ds_read_b128.
// c2 epilogue buffer aliases h1hi (after barrier) -> 37 KB LDS -> 4 blocks/CU.
__launch_bounds__(256, 4)
__global__ void conv12_kernel(
    const float* __restrict__ x, const float* __restrict__ w1,
    const unsigned short* __restrict__ w2hi, const unsigned short* __restrict__ w2lo,
    const float* __restrict__ so1, const float* __restrict__ so2,
    float* __restrict__ h2)
{
    __shared__ unsigned short h1hi[NROW * H1S];   // 18496 B; c2 (16640 B) aliases after K-loop
    __shared__ unsigned short h1lo[NROW * H1S];

    int t  = threadIdx.x;
    int b  = blockIdx.x;
    int u0 = blockIdx.y * TP2;
    int q0 = 3 * u0;
    int wv = __builtin_amdgcn_readfirstlane(t >> 6);  // wave id = co-tile
    int l  = t & 63;
    int m  = l & 15;
    int qd = l >> 4;

    // ---- stage 1: conv1 + bn1 + pool + relu, bf16 hi/lo split ----
    float wr[2][9];
    float s1r[2], o1r[2];
    #pragma unroll
    for (int h = 0; h < 2; ++h) {
        int ch = l + 64*h;
        #pragma unroll
        for (int j = 0; j < 9; ++j) wr[h][j] = w1[ch*9 + j];
        s1r[h] = so1[ch]; o1r[h] = so1[128 + ch];
    }
    for (int s = 0; s < 17; ++s) {
        int r = 4*s + wv;              // local h1 row, wave-uniform
        int xbase = 2*(q0 + r);
        float xv[3][5];
        #pragma unroll
        for (int ci = 0; ci < 3; ++ci) {
            const float* xp = x + (b*3 + ci)*SIGLEN;
            #pragma unroll
            for (int d = 0; d < 5; ++d) {
                int xi = xbase + d; xi = xi < SIGLEN ? xi : SIGLEN - 1;
                xv[ci][d] = xp[xi];
            }
        }
        #pragma unroll
        for (int h = 0; h < 2; ++h) {
            float r0 = 0.f, r1 = 0.f, r2 = 0.f;
            #pragma unroll
            for (int ci = 0; ci < 3; ++ci) {
                float wA = wr[h][ci*3], wB = wr[h][ci*3+1], wC = wr[h][ci*3+2];
                r0 = fmaf(xv[ci][0], wA, fmaf(xv[ci][1], wB, fmaf(xv[ci][2], wC, r0)));
                r1 = fmaf(xv[ci][1], wA, fmaf(xv[ci][2], wB, fmaf(xv[ci][3], wC, r1)));
                r2 = fmaf(xv[ci][2], wA, fmaf(xv[ci][3], wB, fmaf(xv[ci][4], wC, r2)));
            }
            float mx = fmaxf(r0, fmaxf(r1, r2));
            float v  = fmaxf(fmaf(s1r[h], mx, o1r[h]), 0.f);
            unsigned short hi = f2bf(v);
            unsigned short lo = f2bf(v - bf2f(hi));
            h1hi[r*H1S + l + 64*h] = hi;
            h1lo[r*H1S + l + 64*h] = lo;
        }
    }
    __syncthreads();

    // ---- stage 2: MFMA GEMM, wave owns co-tile wv ----
    f32x4 acc[4] = {(f32x4)(0.f), (f32x4)(0.f), (f32x4)(0.f), (f32x4)(0.f)};

    const unsigned short* whb = w2hi + wv*512 + m*32 + qd*8;
    const unsigned short* wlb = w2lo + wv*512 + m*32 + qd*8;

    for (int k = 0; k < 5; ++k) {
        #pragma unroll
        for (int cb = 0; cb < 4; ++cb) {
            int st = k*4 + cb;
            s16x8 wh = *(const s16x8*)(whb + st*2048);
            s16x8 wl = *(const s16x8*)(wlb + st*2048);
            #pragma unroll
            for (int pt = 0; pt < 4; ++pt) {
                int row = pt*16 + m + k;
                s16x8 ah = *(const s16x8*)&h1hi[row*H1S + cb*32 + qd*8];
                s16x8 al = *(const s16x8*)&h1lo[row*H1S + cb*32 + qd*8];
                acc[pt] = __builtin_amdgcn_mfma_f32_16x16x32_bf16(ah, wh, acc[pt], 0, 0, 0);
                acc[pt] = __builtin_amdgcn_mfma_f32_16x16x32_bf16(al, wh, acc[pt], 0, 0, 0);
                acc[pt] = __builtin_amdgcn_mfma_f32_16x16x32_bf16(ah, wl, acc[pt], 0, 0, 0);
            }
        }
    }
    __syncthreads();   // all waves done reading h1hi before aliasing as c2

    // D layout: pos = pt*16 + qd*4 + rg, co = wv*16 + m
    float* c2 = (float*)h1hi;   // [64 pos][65]
    #pragma unroll
    for (int pt = 0; pt < 4; ++pt)
        #pragma unroll
        for (int rg = 0; rg < 4; ++rg)
            c2[(pt*16 + qd*4 + rg)*65 + wv*16 + m] = acc[pt][rg];
    __syncthreads();

    // ---- pool(3,3) + bn2 + relu -> h2[b][u][co] (coalesced) ----
    #pragma unroll
    for (int it = 0; it < 6; ++it) {
        int idx = t + it*256;
        if (idx < TP2*64) {
            int ul = idx >> 6, co = idx & 63;
            int u = u0 + ul;
            if (u < L2OUT) {
                float v0 = c2[(3*ul  )*65 + co];
                float v1 = c2[(3*ul+1)*65 + co];
                float v2 = c2[(3*ul+2)*65 + co];
                float mm = fmaxf(v0, fmaxf(v1, v2));
                h2[(b*L2OUT + u)*64 + co] = fmaxf(fmaf(so2[co], mm, so2[64 + co]), 0.f);
            }
        }
    }
}

// ---------------- conv3+bn3+pool+relu -> flattened xs ----------------
__launch_bounds__(256)
__global__ void conv3_kernel(
    const float* __restrict__ h2, const float* __restrict__ w3t,
    const float* __restrict__ so3, float* __restrict__ xs)
{
    __shared__ float h2l[64 * 345];
    __shared__ float w3l[64 * 192];
    int b = blockIdx.x;
    int t = threadIdx.x;
    for (int i = t; i < 64 * L2OUT; i += 256) {
        int p = i >> 6, ci = i & 63;
        h2l[ci*345 + p] = h2[(b*L2OUT + p)*64 + ci];
    }
    for (int i = t; i < 64 * 192; i += 256) w3l[i] = w3t[i];
    __syncthreads();

    int co0 = (t & 15) * 4;
    int tu  = t >> 4;  // 0..15
    float s[4], o[4];
    #pragma unroll
    for (int c = 0; c < 4; ++c) { s[c] = so3[co0 + c]; o[c] = so3[64 + co0 + c]; }

    for (int uu = 0; uu < 11; ++uu) {
        int u = tu * 11 + uu;
        if (u < L3OUT) {
            float acc[4][3];
            #pragma unroll
            for (int c = 0; c < 4; ++c)
                #pragma unroll
                for (int p = 0; p < 3; ++p) acc[c][p] = 0.f;
            for (int ci = 0; ci < 64; ++ci) {
                float hv[5];
                #pragma unroll
                for (int j = 0; j < 5; ++j) hv[j] = h2l[ci*345 + 2*u + j];
                const float* wp = &w3l[ci * 192 + co0];
                #pragma unroll
                for (int k = 0; k < 3; ++k) {
                    float4 wv = *(const float4*)(wp + k * 64);
                    #pragma unroll
                    for (int p = 0; p < 3; ++p) {
                        float h = hv[p + k];
                        acc[0][p] += h * wv.x;
                        acc[1][p] += h * wv.y;
                        acc[2][p] += h * wv.z;
                        acc[3][p] += h * wv.w;
                    }
                }
            }
            #pragma unroll
            for (int c = 0; c < 4; ++c) {
                float mm = fmaxf(acc[c][0], fmaxf(acc[c][1], acc[c][2]));
                xs[b * FCIN + (co0 + c) * L3OUT + u] = fmaxf(s[c] * mm + o[c], 0.f);
            }
        }
    }
}

// ---------------- fc1 (10752 -> 48), split-K partials ----------------
// grid (64 batch-groups, 8 K-chunks of 1344). Partials reduced in fc234.
__launch_bounds__(256)
__global__ void fc1_kernel(
    const float* __restrict__ xs, const float* __restrict__ w,
    float* __restrict__ part)
{
    int t = threadIdx.x, lane = t & 63, wid = t >> 6;
    int b0 = blockIdx.x * 4;
    int kc = blockIdx.y;
    int o0 = wid * 12;
    float acc[48];
    #pragma unroll
    for (int i = 0; i < 48; ++i) acc[i] = 0.f;

    int kbase = kc * 1344 + lane;
    for (int ki = 0; ki < 21; ++ki) {
        int k = kbase + ki * 64;
        float xv0 = xs[(b0 + 0) * FCIN + k];
        float xv1 = xs[(b0 + 1) * FCIN + k];
        float xv2 = xs[(b0 + 2) * FCIN + k];
        float xv3 = xs[(b0 + 3) * FCIN + k];
        #pragma unroll
        for (int j = 0; j < 12; ++j) {
            float ww = w[(o0 + j) * FCIN + k];
            acc[j]      += xv0 * ww;
            acc[12 + j] += xv1 * ww;
            acc[24 + j] += xv2 * ww;
            acc[36 + j] += xv3 * ww;
        }
    }
    #pragma unroll
    for (int i = 0; i < 48; ++i) {
        #pragma unroll
        for (int off = 32; off > 0; off >>= 1)
            acc[i] += __shfl_xor(acc[i], off, 64);
    }
    if (lane == 0) {
        #pragma unroll
        for (int bb = 0; bb < 4; ++bb)
            #pragma unroll
            for (int j = 0; j < 12; ++j)
                part[((b0 + bb) * 48 + o0 + j) * 8 + kc] = acc[bb * 12 + j];
    }
}

// ---------------- fc1-reduce + fc2/fc3/fc4 + tanh + A = basis @ theta ----------------
__launch_bounds__(256)
__global__ void fc234_kernel(
    const float* __restrict__ part, const float* __restrict__ fc1_b,
    const float* __restrict__ fc2_w, const float* __restrict__ fc2_b,
    const float* __restrict__ fc3_w, const float* __restrict__ fc3_b,
    const float* __restrict__ fc4_w, const float* __restrict__ fc4_b,
    const float* __restrict__ basis, float* __restrict__ A)
{
    __shared__ float xsl[256 * 49];
    __shared__ float w2l[1536], w3l[512], w4l[80];
    __shared__ float b2l[32], b3l[16], b4l[8], basl[60];
    int t = threadIdx.x;
    for (int i = t; i < 256 * 48; i += 256) {
        const float4* p = (const float4*)&part[i * 8];
        float4 pa = p[0], pb = p[1];
        float sv = ((pa.x + pa.y) + (pa.z + pa.w)) + ((pb.x + pb.y) + (pb.z + pb.w));
        xsl[(i / 48) * 49 + (i % 48)] = fmaxf(sv + fc1_b[i % 48], 0.f);
    }
    for (int i = t; i < 1536; i += 256) w2l[i] = fc2_w[i];
    for (int i = t; i < 512;  i += 256) w3l[i] = fc3_w[i];
    if (t < 80) w4l[t] = fc4_w[t];
    if (t < 32) b2l[t] = fc2_b[t];
    if (t < 16) b3l[t] = fc3_b[t];
    if (t < 5)  b4l[t] = fc4_b[t];
    if (t < 60) basl[t] = basis[t];
    __syncthreads();

    const float* xin = &xsl[t * 49];
    float h[32];
    #pragma unroll 4
    for (int o = 0; o < 32; ++o) {
        float sv = b2l[o];
        for (int i = 0; i < 48; ++i) sv += w2l[o * 48 + i] * xin[i];
        h[o] = fmaxf(sv, 0.f);
    }
    float g[16];
    #pragma unroll 4
    for (int o = 0; o < 16; ++o) {
        float sv = b3l[o];
        for (int i = 0; i < 32; ++i) sv += w3l[o * 32 + i] * h[i];
        g[o] = fmaxf(sv, 0.f);
    }
    float th[5];
    #pragma unroll
    for (int o = 0; o < 5; ++o) {
        float sv = b4l[o];
        for (int i = 0; i < 16; ++i) sv += w4l[o * 16 + i] * g[i];
        th[o] = tanhf(sv);
    }
    #pragma unroll
    for (int j = 0; j < 12; ++j) {
        float sv = 0.f;
        #pragma unroll
        for (int d = 0; d < 5; ++d) sv += basl[j * 5 + d] * th[d];
        A[t * 12 + j] = sv;
    }
}

// ---------------- CPAB integrate (7 iters) + interp + transpose ----------------
__launch_bounds__(256)
__global__ void warp_kernel(
    const float* __restrict__ x, const float* __restrict__ A,
    float* __restrict__ out)
{
    __shared__ float Al[12];
    int b = blockIdx.x;
    int i = blockIdx.y * 256 + threadIdx.x;  // 0..2047
    if (threadIdx.x < 12) Al[threadIdx.x] = A[b * 12 + threadIdx.x];
    __syncthreads();

    float xp = (float)i / 2047.f;
    float t  = 1.f;
    for (int it = 0; it < 7; ++it) {
        int c = (int)floorf(xp * 6.f);
        c = min(max(c, 0), 5);
        float a  = Al[2 * c], bb = Al[2 * c + 1];
        float v  = a * xp + bb;
        float xb = (v >= 0.f) ? (float)(c + 1) / 6.f : (float)c / 6.f;
        bool  big_a = fabsf(a) > 1e-8f;
        float a_s = big_a ? a : 1.f;
        float z   = xp + bb / a_s;
        float zb  = xb + bb / a_s;
        float zden = (fabsf(z) > 1e-12f) ? z : 1e-12f;
        float ratio = zb / zden;
        float t_exp = logf(fmaxf(ratio, 1e-12f)) / a_s;
        float v_s   = (fabsf(v) > 1e-12f) ? v : 1.f;
        float t_lin = (xb - xp) / v_s;
        float thit  = big_a ? t_exp : t_lin;
        bool valid  = (fabsf(v) > 1e-12f) && (thit > 0.f) && ((big_a ? ratio : 1.f) > 0.f);
        if (!valid) thit = __builtin_inff();
        float tau   = fminf(t, thit);
        float x_new = big_a ? (z * expf(a * tau) - (z - xp)) : (xp + bb * tau);
        bool hit    = (thit <= t);
        float nudge = (v >= 0.f) ? 1e-6f : -1e-6f;
        xp = hit ? (xb + nudge) : x_new;
        xp = fminf(fmaxf(xp, 0.f), 1.f);
        t  = fmaxf(t - tau, 0.f);
    }
    float p = fminf(fmaxf(xp, 0.f), 1.f) * 2047.f;
    int i0 = (int)floorf(p);
    i0 = min(max(i0, 0), 2046);
    float w = p - (float)i0;
    #pragma unroll
    for (int c = 0; c < 3; ++c) {
        const float* d = &x[(b * 3 + c) * SIGLEN];
        out[(b * 3 + c) * SIGLEN + i] = d[i0] * (1.f - w) + d[i0 + 1] * w;
    }
}

// ---------------- launch ----------------
extern "C" void kernel_launch(void* const* d_in, const int* in_sizes, int n_in,
                              void* d_out, int out_size, void* d_ws, size_t ws_size,
                              hipStream_t stream) {
    (void)in_sizes; (void)n_in; (void)out_size; (void)ws_size;
    const float* x       = (const float*)d_in[0];
    const float* conv1_w = (const float*)d_in[1];
    const float* conv1_b = (const float*)d_in[2];
    const float* bn1_g   = (const float*)d_in[3];
    const float* bn1_b   = (const float*)d_in[4];
    const float* bn1_m   = (const float*)d_in[5];
    const float* bn1_v   = (const float*)d_in[6];
    const float* conv2_w = (const float*)d_in[7];
    const float* conv2_b = (const float*)d_in[8];
    const float* bn2_g   = (const float*)d_in[9];
    const float* bn2_b   = (const float*)d_in[10];
    const float* bn2_m   = (const float*)d_in[11];
    const float* bn2_v   = (const float*)d_in[12];
    const float* conv3_w = (const float*)d_in[13];
    const float* conv3_b = (const float*)d_in[14];
    const float* bn3_g   = (const float*)d_in[15];
    const float* bn3_b   = (const float*)d_in[16];
    const float* bn3_m   = (const float*)d_in[17];
    const float* bn3_v   = (const float*)d_in[18];
    const float* fc1_w   = (const float*)d_in[19];
    const float* fc1_b   = (const float*)d_in[20];
    const float* fc2_w   = (const float*)d_in[21];
    const float* fc2_b   = (const float*)d_in[22];
    const float* fc3_w   = (const float*)d_in[23];
    const float* fc3_b   = (const float*)d_in[24];
    const float* fc4_w   = (const float*)d_in[25];
    const float* fc4_b   = (const float*)d_in[26];
    const float* basis   = (const float*)d_in[27];

    // workspace layout
    unsigned short* w2hi = (unsigned short*)d_ws;     // 40960 ushort
    unsigned short* w2lo = w2hi + 40960;              // 40960 ushort
    float* ws   = (float*)d_ws;
    float* w3t  = ws + 40960;           // 12288
    float* so1  = w3t + 12288;          // 256
    float* so2  = so1 + 256;            // 128
    float* so3  = so2 + 128;            // 128
    float* h2   = so3 + 128;            // 256*339*64 = 5554176 (layout [b][u][co])
    float* xs   = h2  + 5554176;        // 256*10752
    float* part = xs  + 2752512;        // 256*48*8 = 98304
    float* Aws  = part + 98304;         // 256*12
    // total ~8.46M floats ≈ 33.9 MB

    prep_kernel<<<64, 256, 0, stream>>>(
        conv1_b, bn1_g, bn1_b, bn1_m, bn1_v,
        conv2_w, conv2_b, bn2_g, bn2_b, bn2_m, bn2_v,
        conv3_w, conv3_b, bn3_g, bn3_b, bn3_m, bn3_v,
        w2hi, w2lo, w3t, so1, so2, so3);

    dim3 g2(BATCH, (L2OUT + TP2 - 1) / TP2);  // (256, 17)
    conv12_kernel<<<g2, 256, 0, stream>>>(x, conv1_w, w2hi, w2lo, so1, so2, h2);

    conv3_kernel<<<BATCH, 256, 0, stream>>>(h2, w3t, so3, xs);

    dim3 gfc(BATCH / 4, 8);  // (64, 8) split-K
    fc1_kernel<<<gfc, 256, 0, stream>>>(xs, fc1_w, part);

    fc234_kernel<<<1, 256, 0, stream>>>(part, fc1_b, fc2_w, fc2_b, fc3_w, fc3_b,
                                        fc4_w, fc4_b, basis, Aws);

    dim3 g5(BATCH, SIGLEN / 256);  // (256, 8)
    warp_kernel<<<g5, 256, 0, stream>>>(x, Aws, (float*)d_out);
}

// Round 4
// 287.315 us; speedup vs baseline: 2.2084x; 1.1554x over previous
//
#include <hip/hip_runtime.h>
#include <math.h>

// ---------------- problem constants ----------------
#define BATCH   256
#define SIGLEN  2048
#define L1OUT   1022   // conv1(2046) -> pool k3 s2
#define L2OUT   339    // conv2(1018) -> pool k3 s3
#define L3OUT   168    // conv3(337)  -> pool k3 s2
#define FCIN    10752  // 64*168

// conv12 tiling: block = (batch, 21 pooled outputs) -> 63 conv2 positions.
// wave = 2 co-tiles x 2 pos-tiles (halves A-LDS traffic vs 1x4).
#define TP2   21
#define NROW  68
#define H1S   136   // row stride (shorts): 272B rows, 16B-aligned -> ds_read_b128

// conv3 tiling: block = (batch, 28 pooled outputs) -> 57 conv positions
#define TU3   28

typedef float f32x4 __attribute__((ext_vector_type(4)));
typedef short s16x8 __attribute__((ext_vector_type(8)));

__device__ __forceinline__ unsigned short f2bf(float f) {
    unsigned int u = __float_as_uint(f);
    return (unsigned short)((u + 0x7fffu + ((u >> 16) & 1u)) >> 16);
}
__device__ __forceinline__ float bf2f(unsigned short h) {
    return __uint_as_float(((unsigned int)h) << 16);
}

// ---------------- prep: weight frag splits + fc1 permute + BN fold ----------------
__launch_bounds__(256)
__global__ void prep_kernel(
    const float* __restrict__ conv1_b,
    const float* __restrict__ g1, const float* __restrict__ b1,
    const float* __restrict__ m1, const float* __restrict__ v1,
    const float* __restrict__ conv2_w, const float* __restrict__ conv2_b,
    const float* __restrict__ g2, const float* __restrict__ b2,
    const float* __restrict__ m2, const float* __restrict__ v2,
    const float* __restrict__ conv3_w, const float* __restrict__ conv3_b,
    const float* __restrict__ g3, const float* __restrict__ b3,
    const float* __restrict__ m3, const float* __restrict__ v3,
    const float* __restrict__ fc1_w,
    unsigned short* __restrict__ w2hi, unsigned short* __restrict__ w2lo,
    unsigned short* __restrict__ w3hi, unsigned short* __restrict__ w3lo,
    float* __restrict__ wp1,
    float* __restrict__ so1, float* __restrict__ so2, float* __restrict__ so3)
{
    int tid = blockIdx.x * 256 + threadIdx.x;
    int stride = gridDim.x * 256;
    // W2 frag: [(k*4 + ci>>5)*64 + co]*32 + (ci&31), split hi/lo bf16
    for (int i = tid; i < 64*128*5; i += stride) {
        int co = i / 640; int rr = i - co*640; int ci = rr / 5; int k = rr - ci*5;
        float w = conv2_w[i];
        unsigned short hi = f2bf(w);
        unsigned short lo = f2bf(w - bf2f(hi));
        int dst = ((k*4 + (ci >> 5))*64 + co)*32 + (ci & 31);
        w2hi[dst] = hi;
        w2lo[dst] = lo;
    }
    // W3 frag: seg s = k*2 + (ci>>5); dst = (s*64 + co)*32 + (ci&31)
    for (int i = tid; i < 64*64*3; i += stride) {
        int co = i / 192; int r = i - co*192; int ci = r / 3; int k = r - ci*3;
        float w = conv3_w[i];
        unsigned short hi = f2bf(w);
        unsigned short lo = f2bf(w - bf2f(hi));
        int dst = ((k*2 + (ci >> 5))*64 + co)*32 + (ci & 31);
        w3hi[dst] = hi;
        w3lo[dst] = lo;
    }
    // fc1 weight permuted to xs physical layout [u*64+co]
    for (int i = tid; i < 48*FCIN; i += stride) {
        int o = i / FCIN; int ph = i - o*FCIN;
        int u = ph >> 6, co = ph & 63;
        wp1[i] = fc1_w[o*FCIN + co*L3OUT + u];
    }
    if (tid < 128) {
        float s = g1[tid] / sqrtf(v1[tid] + 1e-5f);
        so1[tid]       = s;
        so1[128 + tid] = (conv1_b[tid] - m1[tid]) * s + b1[tid];
    }
    if (tid < 64) {
        float s2 = g2[tid] / sqrtf(v2[tid] + 1e-5f);
        so2[tid]      = s2;
        so2[64 + tid] = (conv2_b[tid] - m2[tid]) * s2 + b2[tid];
        float s3 = g3[tid] / sqrtf(v3[tid] + 1e-5f);
        so3[tid]      = s3;
        so3[64 + tid] = (conv3_b[tid] - m3[tid]) * s3 + b3[tid];
    }
}

// ---------------- fused conv1(fp32) -> conv2 split-bf16 MFMA ----------------
// Wave = (co-pair cp, pos-pair pp): owns co-tiles {2cp,2cp+1} x pos-tiles {2pp,2pp+1}.
// h2 written as packed bf16 hi|lo uint, layout [b][u][co].
__launch_bounds__(256, 4)
__global__ void conv12_kernel(
    const float* __restrict__ x, const float* __restrict__ w1,
    const unsigned short* __restrict__ w2hi, const unsigned short* __restrict__ w2lo,
    const float* __restrict__ so1, const float* __restrict__ so2,
    unsigned int* __restrict__ h2p)
{
    __shared__ unsigned short h1hi[NROW * H1S];   // 18496 B; c2 (16640 B) aliases after K-loop
    __shared__ unsigned short h1lo[NROW * H1S];

    int t  = threadIdx.x;
    int b  = blockIdx.x;
    int u0 = blockIdx.y * TP2;
    int q0 = 3 * u0;
    int wv = __builtin_amdgcn_readfirstlane(t >> 6);
    int l  = t & 63;
    int m  = l & 15;
    int qd = l >> 4;
    int cp = wv & 1;    // co-pair
    int pp = wv >> 1;   // pos-pair

    // ---- stage 1: conv1 + bn1 + pool + relu, bf16 hi/lo split ----
    float wr[2][9];
    float s1r[2], o1r[2];
    #pragma unroll
    for (int h = 0; h < 2; ++h) {
        int ch = l + 64*h;
        #pragma unroll
        for (int j = 0; j < 9; ++j) wr[h][j] = w1[ch*9 + j];
        s1r[h] = so1[ch]; o1r[h] = so1[128 + ch];
    }
    for (int s = 0; s < 17; ++s) {
        int r = 4*s + wv;
        int xbase = 2*(q0 + r);
        float xv[3][5];
        #pragma unroll
        for (int ci = 0; ci < 3; ++ci) {
            const float* xp = x + (b*3 + ci)*SIGLEN;
            #pragma unroll
            for (int d = 0; d < 5; ++d) {
                int xi = xbase + d; xi = xi < SIGLEN ? xi : SIGLEN - 1;
                xv[ci][d] = xp[xi];
            }
        }
        #pragma unroll
        for (int h = 0; h < 2; ++h) {
            float r0 = 0.f, r1 = 0.f, r2 = 0.f;
            #pragma unroll
            for (int ci = 0; ci < 3; ++ci) {
                float wA = wr[h][ci*3], wB = wr[h][ci*3+1], wC = wr[h][ci*3+2];
                r0 = fmaf(xv[ci][0], wA, fmaf(xv[ci][1], wB, fmaf(xv[ci][2], wC, r0)));
                r1 = fmaf(xv[ci][1], wA, fmaf(xv[ci][2], wB, fmaf(xv[ci][3], wC, r1)));
                r2 = fmaf(xv[ci][2], wA, fmaf(xv[ci][3], wB, fmaf(xv[ci][4], wC, r2)));
            }
            float mx = fmaxf(r0, fmaxf(r1, r2));
            float v  = fmaxf(fmaf(s1r[h], mx, o1r[h]), 0.f);
            unsigned short hi = f2bf(v);
            unsigned short lo = f2bf(v - bf2f(hi));
            h1hi[r*H1S + l + 64*h] = hi;
            h1lo[r*H1S + l + 64*h] = lo;
        }
    }
    __syncthreads();

    // ---- stage 2: MFMA, 2 co-tiles x 2 pos-tiles per wave ----
    f32x4 acc[2][2] = {{(f32x4)(0.f), (f32x4)(0.f)}, {(f32x4)(0.f), (f32x4)(0.f)}};

    const unsigned short* whb0 = w2hi + (2*cp  )*512 + m*32 + qd*8;
    const unsigned short* whb1 = w2hi + (2*cp+1)*512 + m*32 + qd*8;
    const unsigned short* wlb0 = w2lo + (2*cp  )*512 + m*32 + qd*8;
    const unsigned short* wlb1 = w2lo + (2*cp+1)*512 + m*32 + qd*8;

    for (int k = 0; k < 5; ++k) {
        #pragma unroll
        for (int cb = 0; cb < 4; ++cb) {
            int st = k*4 + cb;
            s16x8 wh0 = *(const s16x8*)(whb0 + st*2048);
            s16x8 wl0 = *(const s16x8*)(wlb0 + st*2048);
            s16x8 wh1 = *(const s16x8*)(whb1 + st*2048);
            s16x8 wl1 = *(const s16x8*)(wlb1 + st*2048);
            #pragma unroll
            for (int ptl = 0; ptl < 2; ++ptl) {
                int row = (2*pp + ptl)*16 + m + k;
                s16x8 ah = *(const s16x8*)&h1hi[row*H1S + cb*32 + qd*8];
                s16x8 al = *(const s16x8*)&h1lo[row*H1S + cb*32 + qd*8];
                acc[0][ptl] = __builtin_amdgcn_mfma_f32_16x16x32_bf16(ah, wh0, acc[0][ptl], 0, 0, 0);
                acc[0][ptl] = __builtin_amdgcn_mfma_f32_16x16x32_bf16(al, wh0, acc[0][ptl], 0, 0, 0);
                acc[0][ptl] = __builtin_amdgcn_mfma_f32_16x16x32_bf16(ah, wl0, acc[0][ptl], 0, 0, 0);
                acc[1][ptl] = __builtin_amdgcn_mfma_f32_16x16x32_bf16(ah, wh1, acc[1][ptl], 0, 0, 0);
                acc[1][ptl] = __builtin_amdgcn_mfma_f32_16x16x32_bf16(al, wh1, acc[1][ptl], 0, 0, 0);
                acc[1][ptl] = __builtin_amdgcn_mfma_f32_16x16x32_bf16(ah, wl1, acc[1][ptl], 0, 0, 0);
            }
        }
    }
    __syncthreads();   // all waves done reading h1 before aliasing as c2

    float* c2 = (float*)h1hi;   // [64 pos][65]
    #pragma unroll
    for (int ctl = 0; ctl < 2; ++ctl)
        #pragma unroll
        for (int ptl = 0; ptl < 2; ++ptl)
            #pragma unroll
            for (int rg = 0; rg < 4; ++rg)
                c2[((2*pp + ptl)*16 + qd*4 + rg)*65 + (2*cp + ctl)*16 + m] = acc[ctl][ptl][rg];
    __syncthreads();

    // ---- pool(3,3) + bn2 + relu -> h2p[b][u][co] packed bf16 hi|lo ----
    #pragma unroll
    for (int it = 0; it < 6; ++it) {
        int idx = t + it*256;
        if (idx < TP2*64) {
            int ul = idx >> 6, co = idx & 63;
            int u = u0 + ul;
            if (u < L2OUT) {
                float v0 = c2[(3*ul  )*65 + co];
                float v1 = c2[(3*ul+1)*65 + co];
                float v2 = c2[(3*ul+2)*65 + co];
                float mm = fmaxf(v0, fmaxf(v1, v2));
                float v  = fmaxf(fmaf(so2[co], mm, so2[64 + co]), 0.f);
                unsigned short hi = f2bf(v);
                unsigned short lo = f2bf(v - bf2f(hi));
                h2p[(b*L2OUT + u)*64 + co] = (unsigned int)hi | ((unsigned int)lo << 16);
            }
        }
    }
}

// ---------------- conv3 split-bf16 MFMA + bn3 + pool + relu -> xs[b][u][co] ----------------
__launch_bounds__(256, 4)
__global__ void conv3_kernel(
    const unsigned int* __restrict__ h2p,
    const unsigned short* __restrict__ w3hi, const unsigned short* __restrict__ w3lo,
    const float* __restrict__ so3, float* __restrict__ xs)
{
    __shared__ unsigned short h3hi[66 * 72];   // 9504 B x2; c3 (16640 B) aliases h3hi+h3lo
    __shared__ unsigned short h3lo[66 * 72];

    int t  = threadIdx.x;
    int b  = blockIdx.x;
    int u0 = blockIdx.y * TU3;
    int wv = __builtin_amdgcn_readfirstlane(t >> 6);  // wave = co-tile
    int l  = t & 63;
    int m  = l & 15;
    int qd = l >> 4;

    // stage h2 rows 2u0 .. 2u0+65 (clamped)
    for (int i = t; i < 66*64; i += 256) {
        int r = i >> 6, ci = i & 63;
        int g = 2*u0 + r; g = g > (L2OUT-1) ? (L2OUT-1) : g;
        unsigned int v = h2p[(b*L2OUT + g)*64 + ci];
        h3hi[r*72 + ci] = (unsigned short)(v & 0xffffu);
        h3lo[r*72 + ci] = (unsigned short)(v >> 16);
    }
    __syncthreads();

    // B frags register-resident: 6 segs (k*2 + half)
    s16x8 wh[6], wl[6];
    #pragma unroll
    for (int s = 0; s < 6; ++s) {
        wh[s] = *(const s16x8*)(w3hi + s*2048 + (wv*16 + m)*32 + qd*8);
        wl[s] = *(const s16x8*)(w3lo + s*2048 + (wv*16 + m)*32 + qd*8);
    }

    f32x4 acc[4] = {(f32x4)(0.f), (f32x4)(0.f), (f32x4)(0.f), (f32x4)(0.f)};
    #pragma unroll
    for (int pt = 0; pt < 4; ++pt) {
        #pragma unroll
        for (int s = 0; s < 6; ++s) {
            int row = pt*16 + m + (s >> 1);
            int off = (s & 1)*32 + qd*8;
            s16x8 ah = *(const s16x8*)&h3hi[row*72 + off];
            s16x8 al = *(const s16x8*)&h3lo[row*72 + off];
            acc[pt] = __builtin_amdgcn_mfma_f32_16x16x32_bf16(ah, wh[s], acc[pt], 0, 0, 0);
            acc[pt] = __builtin_amdgcn_mfma_f32_16x16x32_bf16(al, wh[s], acc[pt], 0, 0, 0);
            acc[pt] = __builtin_amdgcn_mfma_f32_16x16x32_bf16(ah, wl[s], acc[pt], 0, 0, 0);
        }
    }
    __syncthreads();

    float* c3 = (float*)h3hi;   // [64 pos][65]
    #pragma unroll
    for (int pt = 0; pt < 4; ++pt)
        #pragma unroll
        for (int rg = 0; rg < 4; ++rg)
            c3[(pt*16 + qd*4 + rg)*65 + wv*16 + m] = acc[pt][rg];
    __syncthreads();

    // pool(3,2) + bn3 + relu -> xs[b][u*64+co] (coalesced)
    #pragma unroll
    for (int it = 0; it < 7; ++it) {
        int idx = t + it*256;
        if (idx < TU3*64) {
            int ul = idx >> 6, co = idx & 63;
            int p = 2*ul;
            float v0 = c3[(p  )*65 + co];
            float v1 = c3[(p+1)*65 + co];
            float v2 = c3[(p+2)*65 + co];
            float mm = fmaxf(v0, fmaxf(v1, v2));
            xs[b*FCIN + (u0 + ul)*64 + co] = fmaxf(fmaf(so3[co], mm, so3[64 + co]), 0.f);
        }
    }
}

// ---------------- fc1 (10752 -> 48), split-K partials (wp1 permuted weights) ----------------
__launch_bounds__(256)
__global__ void fc1_kernel(
    const float* __restrict__ xs, const float* __restrict__ w,
    float* __restrict__ part)
{
    int t = threadIdx.x, lane = t & 63, wid = t >> 6;
    int b0 = blockIdx.x * 4;
    int kc = blockIdx.y;
    int o0 = wid * 12;
    float acc[48];
    #pragma unroll
    for (int i = 0; i < 48; ++i) acc[i] = 0.f;

    int kbase = kc * 1344 + lane;
    for (int ki = 0; ki < 21; ++ki) {
        int k = kbase + ki * 64;
        float xv0 = xs[(b0 + 0) * FCIN + k];
        float xv1 = xs[(b0 + 1) * FCIN + k];
        float xv2 = xs[(b0 + 2) * FCIN + k];
        float xv3 = xs[(b0 + 3) * FCIN + k];
        #pragma unroll
        for (int j = 0; j < 12; ++j) {
            float ww = w[(o0 + j) * FCIN + k];
            acc[j]      += xv0 * ww;
            acc[12 + j] += xv1 * ww;
            acc[24 + j] += xv2 * ww;
            acc[36 + j] += xv3 * ww;
        }
    }
    #pragma unroll
    for (int i = 0; i < 48; ++i) {
        #pragma unroll
        for (int off = 32; off > 0; off >>= 1)
            acc[i] += __shfl_xor(acc[i], off, 64);
    }
    if (lane == 0) {
        #pragma unroll
        for (int bb = 0; bb < 4; ++bb)
            #pragma unroll
            for (int j = 0; j < 12; ++j)
                part[((b0 + bb) * 48 + o0 + j) * 8 + kc] = acc[bb * 12 + j];
    }
}

// ---------------- fc1-reduce + fc2/fc3/fc4 + tanh + A = basis @ theta ----------------
__launch_bounds__(256)
__global__ void fc234_kernel(
    const float* __restrict__ part, const float* __restrict__ fc1_b,
    const float* __restrict__ fc2_w, const float* __restrict__ fc2_b,
    const float* __restrict__ fc3_w, const float* __restrict__ fc3_b,
    const float* __restrict__ fc4_w, const float* __restrict__ fc4_b,
    const float* __restrict__ basis, float* __restrict__ A)
{
    __shared__ float xsl[256 * 49];
    __shared__ float w2l[1536], w3l[512], w4l[80];
    __shared__ float b2l[32], b3l[16], b4l[8], basl[60];
    int t = threadIdx.x;
    for (int i = t; i < 256 * 48; i += 256) {
        const float4* p = (const float4*)&part[i * 8];
        float4 pa = p[0], pb = p[1];
        float sv = ((pa.x + pa.y) + (pa.z + pa.w)) + ((pb.x + pb.y) + (pb.z + pb.w));
        xsl[(i / 48) * 49 + (i % 48)] = fmaxf(sv + fc1_b[i % 48], 0.f);
    }
    for (int i = t; i < 1536; i += 256) w2l[i] = fc2_w[i];
    for (int i = t; i < 512;  i += 256) w3l[i] = fc3_w[i];
    if (t < 80) w4l[t] = fc4_w[t];
    if (t < 32) b2l[t] = fc2_b[t];
    if (t < 16) b3l[t] = fc3_b[t];
    if (t < 5)  b4l[t] = fc4_b[t];
    if (t < 60) basl[t] = basis[t];
    __syncthreads();

    const float* xin = &xsl[t * 49];
    float h[32];
    #pragma unroll 4
    for (int o = 0; o < 32; ++o) {
        float sv = b2l[o];
        for (int i = 0; i < 48; ++i) sv += w2l[o * 48 + i] * xin[i];
        h[o] = fmaxf(sv, 0.f);
    }
    float g[16];
    #pragma unroll 4
    for (int o = 0; o < 16; ++o) {
        float sv = b3l[o];
        for (int i = 0; i < 32; ++i) sv += w3l[o * 32 + i] * h[i];
        g[o] = fmaxf(sv, 0.f);
    }
    float th[5];
    #pragma unroll
    for (int o = 0; o < 5; ++o) {
        float sv = b4l[o];
        for (int i = 0; i < 16; ++i) sv += w4l[o * 16 + i] * g[i];
        th[o] = tanhf(sv);
    }
    #pragma unroll
    for (int j = 0; j < 12; ++j) {
        float sv = 0.f;
        #pragma unroll
        for (int d = 0; d < 5; ++d) sv += basl[j * 5 + d] * th[d];
        A[t * 12 + j] = sv;
    }
}

// ---------------- CPAB integrate (7 iters) + interp + transpose ----------------
__launch_bounds__(256)
__global__ void warp_kernel(
    const float* __restrict__ x, const float* __restrict__ A,
    float* __restrict__ out)
{
    __shared__ float Al[12];
    int b = blockIdx.x;
    int i = blockIdx.y * 256 + threadIdx.x;
    if (threadIdx.x < 12) Al[threadIdx.x] = A[b * 12 + threadIdx.x];
    __syncthreads();

    float xp = (float)i / 2047.f;
    float t  = 1.f;
    for (int it = 0; it < 7; ++it) {
        int c = (int)floorf(xp * 6.f);
        c = min(max(c, 0), 5);
        float a  = Al[2 * c], bb = Al[2 * c + 1];
        float v  = a * xp + bb;
        float xb = (v >= 0.f) ? (float)(c + 1) / 6.f : (float)c / 6.f;
        bool  big_a = fabsf(a) > 1e-8f;
        float a_s = big_a ? a : 1.f;
        float z   = xp + bb / a_s;
        float zb  = xb + bb / a_s;
        float zden = (fabsf(z) > 1e-12f) ? z : 1e-12f;
        float ratio = zb / zden;
        float t_exp = logf(fmaxf(ratio, 1e-12f)) / a_s;
        float v_s   = (fabsf(v) > 1e-12f) ? v : 1.f;
        float t_lin = (xb - xp) / v_s;
        float thit  = big_a ? t_exp : t_lin;
        bool valid  = (fabsf(v) > 1e-12f) && (thit > 0.f) && ((big_a ? ratio : 1.f) > 0.f);
        if (!valid) thit = __builtin_inff();
        float tau   = fminf(t, thit);
        float x_new = big_a ? (z * expf(a * tau) - (z - xp)) : (xp + bb * tau);
        bool hit    = (thit <= t);
        float nudge = (v >= 0.f) ? 1e-6f : -1e-6f;
        xp = hit ? (xb + nudge) : x_new;
        xp = fminf(fmaxf(xp, 0.f), 1.f);
        t  = fmaxf(t - tau, 0.f);
    }
    float p = fminf(fmaxf(xp, 0.f), 1.f) * 2047.f;
    int i0 = (int)floorf(p);
    i0 = min(max(i0, 0), 2046);
    float w = p - (float)i0;
    #pragma unroll
    for (int c = 0; c < 3; ++c) {
        const float* d = &x[(b * 3 + c) * SIGLEN];
        out[(b * 3 + c) * SIGLEN + i] = d[i0] * (1.f - w) + d[i0 + 1] * w;
    }
}

// ---------------- launch ----------------
extern "C" void kernel_launch(void* const* d_in, const int* in_sizes, int n_in,
                              void* d_out, int out_size, void* d_ws, size_t ws_size,
                              hipStream_t stream) {
    (void)in_sizes; (void)n_in; (void)out_size; (void)ws_size;
    const float* x       = (const float*)d_in[0];
    const float* conv1_w = (const float*)d_in[1];
    const float* conv1_b = (const float*)d_in[2];
    const float* bn1_g   = (const float*)d_in[3];
    const float* bn1_b   = (const float*)d_in[4];
    const float* bn1_m   = (const float*)d_in[5];
    const float* bn1_v   = (const float*)d_in[6];
    const float* conv2_w = (const float*)d_in[7];
    const float* conv2_b = (const float*)d_in[8];
    const float* bn2_g   = (const float*)d_in[9];
    const float* bn2_b   = (const float*)d_in[10];
    const float* bn2_m   = (const float*)d_in[11];
    const float* bn2_v   = (const float*)d_in[12];
    const float* conv3_w = (const float*)d_in[13];
    const float* conv3_b = (const float*)d_in[14];
    const float* bn3_g   = (const float*)d_in[15];
    const float* bn3_b   = (const float*)d_in[16];
    const float* bn3_m   = (const float*)d_in[17];
    const float* bn3_v   = (const float*)d_in[18];
    const float* fc1_w   = (const float*)d_in[19];
    const float* fc1_b   = (const float*)d_in[20];
    const float* fc2_w   = (const float*)d_in[21];
    const float* fc2_b   = (const float*)d_in[22];
    const float* fc3_w   = (const float*)d_in[23];
    const float* fc3_b   = (const float*)d_in[24];
    const float* fc4_w   = (const float*)d_in[25];
    const float* fc4_b   = (const float*)d_in[26];
    const float* basis   = (const float*)d_in[27];

    // workspace layout (floats unless noted)
    unsigned short* w2hi = (unsigned short*)d_ws;       // 40960 ush
    unsigned short* w2lo = w2hi + 40960;                // 40960 ush
    unsigned short* w3hi = w2lo + 40960;                // 12288 ush
    unsigned short* w3lo = w3hi + 12288;                // 12288 ush
    float* ws   = (float*)d_ws;
    float* so1  = ws + 53248;           // 256
    float* so2  = so1 + 256;            // 128
    float* so3  = so2 + 128;            // 128
    float* wp1  = so3 + 128;            // 48*10752 = 516096
    unsigned int* h2p = (unsigned int*)(wp1 + 516096);  // 256*339*64 = 5554176 uints
    float* xs   = wp1 + 516096 + 5554176;  // 256*10752
    float* part = xs  + 2752512;        // 256*48*8 = 98304
    float* Aws  = part + 98304;         // 256*12
    // total ≈ 8.98M floats ≈ 35.9 MB

    prep_kernel<<<256, 256, 0, stream>>>(
        conv1_b, bn1_g, bn1_b, bn1_m, bn1_v,
        conv2_w, conv2_b, bn2_g, bn2_b, bn2_m, bn2_v,
        conv3_w, conv3_b, bn3_g, bn3_b, bn3_m, bn3_v,
        fc1_w, w2hi, w2lo, w3hi, w3lo, wp1, so1, so2, so3);

    dim3 g2(BATCH, (L2OUT + TP2 - 1) / TP2);  // (256, 17)
    conv12_kernel<<<g2, 256, 0, stream>>>(x, conv1_w, w2hi, w2lo, so1, so2, h2p);

    dim3 g3(BATCH, L3OUT / TU3);  // (256, 6)
    conv3_kernel<<<g3, 256, 0, stream>>>(h2p, w3hi, w3lo, so3, xs);

    dim3 gfc(BATCH / 4, 8);  // (64, 8) split-K
    fc1_kernel<<<gfc, 256, 0, stream>>>(xs, wp1, part);

    fc234_kernel<<<1, 256, 0, stream>>>(part, fc1_b, fc2_w, fc2_b, fc3_w, fc3_b,
                                        fc4_w, fc4_b, basis, Aws);

    dim3 g5(BATCH, SIGLEN / 256);  // (256, 8)
    warp_kernel<<<g5, 256, 0, stream>>>(x, Aws, (float*)d_out);
}